// Round 4
// baseline (135.664 us; speedup 1.0000x reference)
//
#include <hip/hip_runtime.h>
#include <math.h>

// CRF forward: B=64, C=2, T=65536.
// Log-semiring matrix scan: alpha_t = A_t (x) alpha_{t-1},
//   A_t[i][j] = trans[i][j] + emit_t[i]
// Associative => parallel chunked scan with 2x2 transfer matrices.
// Base-2 logs: LSE = 1x v_exp_f32 + 1x v_log_f32 (both native HW).
// Single fused kernel: block-local scan+reduce, last block (atomic ticket)
// does the cross-segment combine + batch LSE + loss write.

#define T_LEN   65536
#define SEG     4096      // elements per block
#define NT      256       // threads per block (16 elems/thread)
#define NSEG    16        // SEG * NSEG = T_LEN
#define NBATCH  64
#define NBLK    (NBATCH * NSEG)   // 1024

// __builtin_amdgcn_exp2f = v_exp_f32 (2^x); __builtin_amdgcn_logf = v_log_f32 (log2 x)
__device__ __forceinline__ float lse2(float a, float b) {
    float m = fmaxf(a, b);
    float d = fminf(a, b) - m;          // <= 0; -1e30 inputs give exp2 -> 0, no NaN
    return m + __builtin_amdgcn_logf(1.0f + __builtin_amdgcn_exp2f(d));
}

// C = A (x) B in log-semiring; A = later chunk, B = earlier. (x,y,z,w)=(00,01,10,11)
__device__ __forceinline__ float4 mcomb(float4 A, float4 B) {
    return make_float4(lse2(A.x + B.x, A.y + B.z),
                       lse2(A.x + B.y, A.y + B.w),
                       lse2(A.z + B.x, A.w + B.z),
                       lse2(A.z + B.y, A.w + B.w));
}

__global__ __launch_bounds__(NT) void crf_fused_kernel(
    const float* __restrict__ logits,   // (B, 2, T) flat
    const float* __restrict__ trans,    // (2,2)
    float* __restrict__ out,            // out[0]=loss, out[1..]=decoded
    float4* __restrict__ wsM,           // 1024 chunk matrices
    unsigned int* __restrict__ counter) // zeroed by memset node each launch
{
    __shared__ float4 red[NT];
    __shared__ int s_last;

    const int blk = blockIdx.x;         // 0..1023
    const int b   = blk >> 4;           // batch
    const int seg = blk & (NSEG - 1);   // segment within batch
    const int tid = threadIdx.x;
    const float K = 1.4426950408889634f;    // log2(e)

    // Each thread owns 16 consecutive timesteps: direct float4 loads, no LDS.
    const float* l0 = logits + (size_t)b * (2 * T_LEN) + seg * SEG + tid * 16;
    const float* l1 = l0 + T_LEN;
    float* dec = out + 1 + (size_t)b * T_LEN + seg * SEG + tid * 16;

    float4 a[4], c[4];
    #pragma unroll
    for (int j = 0; j < 4; ++j) {
        a[j] = ((const float4*)l0)[j];
        c[j] = ((const float4*)l1)[j];
    }
    #pragma unroll
    for (int j = 0; j < 4; ++j) {
        ((float4*)dec)[j] = make_float4(a[j].x >= c[j].x ? 0.0f : 1.0f,
                                        a[j].y >= c[j].y ? 0.0f : 1.0f,
                                        a[j].z >= c[j].z ? 0.0f : 1.0f,
                                        a[j].w >= c[j].w ? 0.0f : 1.0f);
    }

    float E0[16], E1[16];
    #pragma unroll
    for (int j = 0; j < 4; ++j) {
        E0[4*j+0] = a[j].x * K; E0[4*j+1] = a[j].y * K;
        E0[4*j+2] = a[j].z * K; E0[4*j+3] = a[j].w * K;
        E1[4*j+0] = c[j].x * K; E1[4*j+1] = c[j].y * K;
        E1[4*j+2] = c[j].z * K; E1[4*j+3] = c[j].w * K;
    }

    const float t00 = trans[0] * K, t01 = trans[1] * K;
    const float t10 = trans[2] * K, t11 = trans[3] * K;

    // ---- per-thread sequential scan over 16 steps (2x2 transfer matrix) ----
    float m00, m01, m10, m11;
    if (blk == 0 && tid == 0) {
        // global t=0: alpha0 = emit_0 as diagonal "matrix"
        m00 = E0[0]; m11 = E1[0]; m01 = -1e30f; m10 = -1e30f;
    } else {
        m00 = t00 + E0[0]; m01 = t01 + E0[0];
        m10 = t10 + E1[0]; m11 = t11 + E1[0];
    }
    #pragma unroll
    for (int j = 1; j < 16; ++j) {
        float n00 = E0[j] + lse2(t00 + m00, t01 + m10);
        float n01 = E0[j] + lse2(t00 + m01, t01 + m11);
        float n10 = E1[j] + lse2(t10 + m00, t11 + m10);
        float n11 = E1[j] + lse2(t10 + m01, t11 + m11);
        m00 = n00; m01 = n01; m10 = n10; m11 = n11;
    }

    // ---- block tree-reduce 256 matrices ----
    red[tid] = make_float4(m00, m01, m10, m11);
    __syncthreads();
    #pragma unroll
    for (int s = NT / 2; s >= 1; s >>= 1) {
        if (tid < s) red[tid] = mcomb(red[tid + s], red[tid]);
        __syncthreads();
    }

    // ---- publish + last-block final combine ----
    if (tid == 0) {
        wsM[blk] = red[0];
        __threadfence();                         // release
        unsigned int old = atomicAdd(counter, 1u);
        s_last = (old == NBLK - 1) ? 1 : 0;
    }
    __syncthreads();
    if (!s_last) return;
    __threadfence();                             // acquire

    if (tid < NBATCH) {                          // exactly one wave
        float4 Acc = wsM[tid * NSEG];
        #pragma unroll
        for (int s = 1; s < NSEG; ++s) Acc = mcomb(wsM[tid * NSEG + s], Acc);
        float ll2 = lse2(lse2(Acc.x, Acc.y), lse2(Acc.z, Acc.w));
        #pragma unroll
        for (int off = 32; off >= 1; off >>= 1) ll2 += __shfl_xor(ll2, off);
        if (tid == 0) out[0] = -(0.6931471805599453f * ll2) * (1.0f / (float)NBATCH);
    }
}

extern "C" void kernel_launch(void* const* d_in, const int* in_sizes, int n_in,
                              void* d_out, int out_size, void* d_ws, size_t ws_size,
                              hipStream_t stream) {
    const float* logits = (const float*)d_in[0];
    // d_in[1] = mask: all-ones and unused by the reference computation
    const float* trans  = (const float*)d_in[2];
    float* out  = (float*)d_out;
    float4* wsM = (float4*)d_ws;                          // 1024 * 16 B
    unsigned int* counter = (unsigned int*)((char*)d_ws + NBLK * sizeof(float4));

    hipMemsetAsync(counter, 0, sizeof(unsigned int), stream);
    crf_fused_kernel<<<NBLK, NT, 0, stream>>>(logits, trans, out, wsM, counter);
}

// Round 5
// 128.061 us; speedup vs baseline: 1.0594x; 1.0594x over previous
//
#include <hip/hip_runtime.h>
#include <math.h>

// CRF forward: B=64, C=2, T=65536.
// Log-semiring matrix scan: alpha_t = A_t (x) alpha_{t-1},
//   A_t[i][j] = trans[i][j] + emit_t[i]
// Associative => parallel chunked scan with 2x2 transfer matrices.
// Base-2 logs: LSE = 1x v_exp_f32 + 1x v_log_f32 (both native HW).
// R5: no register arrays (R4 spilled at VGPR=32 -> scratch latency in the
// serial chain). 512 thr x 8 steps, launch_bounds(512,2) to allow 256 VGPRs.

#define T_LEN   65536
#define NT      512       // threads per block (8 waves)
#define STEPS   8         // timesteps per thread
#define SEG     (NT * STEPS)      // 4096 per block
#define NSEG    16        // segments per batch
#define NBATCH  64
#define NBLK    (NBATCH * NSEG)   // 1024 blocks = 4/CU

// __builtin_amdgcn_exp2f = v_exp_f32 (2^x); __builtin_amdgcn_logf = v_log_f32 (log2 x)
__device__ __forceinline__ float lse2(float a, float b) {
    float m = fmaxf(a, b);
    float d = fminf(a, b) - m;          // <= 0; -1e30 inputs give exp2 -> 0, no NaN
    return m + __builtin_amdgcn_logf(1.0f + __builtin_amdgcn_exp2f(d));
}

// C = A (x) B in log-semiring; A = later chunk, B = earlier. (x,y,z,w)=(00,01,10,11)
__device__ __forceinline__ float4 mcomb(float4 A, float4 B) {
    return make_float4(lse2(A.x + B.x, A.y + B.z),
                       lse2(A.x + B.y, A.y + B.w),
                       lse2(A.z + B.x, A.w + B.z),
                       lse2(A.z + B.y, A.w + B.w));
}

__global__ __launch_bounds__(NT, 2) void crf_fused_kernel(
    const float* __restrict__ logits,   // (B, 2, T) flat
    const float* __restrict__ trans,    // (2,2)
    float* __restrict__ out,            // out[0]=loss, out[1..]=decoded
    float4* __restrict__ wsM,           // 1024 chunk matrices
    unsigned int* __restrict__ counter) // zeroed by memset node each launch
{
    __shared__ float4 red[NT];          // 8 KB
    __shared__ int s_last;

    const int blk = blockIdx.x;         // 0..1023
    const int b   = blk >> 4;           // batch
    const int seg = blk & (NSEG - 1);   // segment within batch
    const int tid = threadIdx.x;
    const float K = 1.4426950408889634f;    // log2(e)

    // Each thread owns 8 consecutive timesteps: two float4 per channel.
    const float* l0 = logits + (size_t)b * (2 * T_LEN) + seg * SEG + tid * STEPS;
    const float* l1 = l0 + T_LEN;
    float* dec = out + 1 + (size_t)b * T_LEN + seg * SEG + tid * STEPS;

    const float4 a0 = ((const float4*)l0)[0];
    const float4 a1 = ((const float4*)l0)[1];
    const float4 c0 = ((const float4*)l1)[0];
    const float4 c1 = ((const float4*)l1)[1];

    ((float4*)dec)[0] = make_float4(a0.x >= c0.x ? 0.0f : 1.0f,
                                    a0.y >= c0.y ? 0.0f : 1.0f,
                                    a0.z >= c0.z ? 0.0f : 1.0f,
                                    a0.w >= c0.w ? 0.0f : 1.0f);
    ((float4*)dec)[1] = make_float4(a1.x >= c1.x ? 0.0f : 1.0f,
                                    a1.y >= c1.y ? 0.0f : 1.0f,
                                    a1.z >= c1.z ? 0.0f : 1.0f,
                                    a1.w >= c1.w ? 0.0f : 1.0f);

    const float t00 = trans[0] * K, t01 = trans[1] * K;
    const float t10 = trans[2] * K, t11 = trans[3] * K;

    // ---- per-thread sequential scan over 8 steps (2x2 transfer matrix) ----
    float m00, m01, m10, m11;
    {
        const float e0 = a0.x * K, e1 = c0.x * K;
        if (blk == 0 && tid == 0) {
            // global t=0: alpha0 = emit_0 as diagonal "matrix"
            m00 = e0; m11 = e1; m01 = -1e30f; m10 = -1e30f;
        } else {
            m00 = t00 + e0; m01 = t01 + e0;
            m10 = t10 + e1; m11 = t11 + e1;
        }
    }
    auto step = [&](float x0, float x1) {
        const float e0 = x0 * K, e1 = x1 * K;
        const float n00 = e0 + lse2(t00 + m00, t01 + m10);
        const float n01 = e0 + lse2(t00 + m01, t01 + m11);
        const float n10 = e1 + lse2(t10 + m00, t11 + m10);
        const float n11 = e1 + lse2(t10 + m01, t11 + m11);
        m00 = n00; m01 = n01; m10 = n10; m11 = n11;
    };
    step(a0.y, c0.y); step(a0.z, c0.z); step(a0.w, c0.w);
    step(a1.x, c1.x); step(a1.y, c1.y); step(a1.z, c1.z); step(a1.w, c1.w);

    // ---- block tree-reduce 512 matrices ----
    red[tid] = make_float4(m00, m01, m10, m11);
    __syncthreads();
    #pragma unroll
    for (int s = NT / 2; s >= 1; s >>= 1) {
        if (tid < s) red[tid] = mcomb(red[tid + s], red[tid]);
        __syncthreads();
    }

    // ---- publish + last-block final combine ----
    if (tid == 0) {
        wsM[blk] = red[0];
        __threadfence();                         // release
        unsigned int old = atomicAdd(counter, 1u);
        s_last = (old == NBLK - 1) ? 1 : 0;
    }
    __syncthreads();
    if (!s_last) return;
    __threadfence();                             // acquire

    if (tid < NBATCH) {                          // exactly one wave
        float4 Acc = wsM[tid * NSEG];
        #pragma unroll
        for (int s = 1; s < NSEG; ++s) Acc = mcomb(wsM[tid * NSEG + s], Acc);
        float ll2 = lse2(lse2(Acc.x, Acc.y), lse2(Acc.z, Acc.w));
        #pragma unroll
        for (int off = 32; off >= 1; off >>= 1) ll2 += __shfl_xor(ll2, off);
        if (tid == 0) out[0] = -(0.6931471805599453f * ll2) * (1.0f / (float)NBATCH);
    }
}

extern "C" void kernel_launch(void* const* d_in, const int* in_sizes, int n_in,
                              void* d_out, int out_size, void* d_ws, size_t ws_size,
                              hipStream_t stream) {
    const float* logits = (const float*)d_in[0];
    // d_in[1] = mask: all-ones and unused by the reference computation
    const float* trans  = (const float*)d_in[2];
    float* out  = (float*)d_out;
    float4* wsM = (float4*)d_ws;                          // 1024 * 16 B
    unsigned int* counter = (unsigned int*)((char*)d_ws + NBLK * sizeof(float4));

    hipMemsetAsync(counter, 0, sizeof(unsigned int), stream);
    crf_fused_kernel<<<NBLK, NT, 0, stream>>>(logits, trans, out, wsM, counter);
}

// Round 6
// 110.775 us; speedup vs baseline: 1.2247x; 1.1560x over previous
//
#include <hip/hip_runtime.h>
#include <math.h>

// CRF forward: B=64, C=2, T=65536.
// Log-semiring matrix scan: alpha_t = A_t (x) alpha_{t-1},
//   A_t[i][j] = trans[i][j] + emit_t[i]
// Parallel chunked scan with 2x2 transfer matrices, base-2 logs
// (LSE = 1x v_exp_f32 + 1x v_log_f32, both native HW).
// R6: streamed loads (no register arrays -> no spills; R4/R5 spilled and the
// scratch reloads sat in the serial chain), shuffle-based wave reduction
// (no LDS tree barriers), two kernels (no device fence / same-address atomic).

#define T_LEN   65536
#define NT      256       // threads per block (4 waves)
#define STEPS   16        // timesteps per thread
#define SEG     (NT * STEPS)      // 4096 per block
#define NSEG    16        // segments per batch
#define NBATCH  64
#define NBLK    (NBATCH * NSEG)   // 1024 blocks

// __builtin_amdgcn_exp2f = v_exp_f32 (2^x); __builtin_amdgcn_logf = v_log_f32 (log2 x)
__device__ __forceinline__ float lse2(float a, float b) {
    float m = fmaxf(a, b);
    float d = fminf(a, b) - m;          // <= 0; -1e30 inputs give exp2 -> 0, no NaN
    return m + __builtin_amdgcn_logf(1.0f + __builtin_amdgcn_exp2f(d));
}

// C = A (x) B in log-semiring; A = later chunk, B = earlier. (x,y,z,w)=(00,01,10,11)
__device__ __forceinline__ float4 mcomb(float4 A, float4 B) {
    return make_float4(lse2(A.x + B.x, A.y + B.z),
                       lse2(A.x + B.y, A.y + B.w),
                       lse2(A.z + B.x, A.w + B.z),
                       lse2(A.z + B.y, A.w + B.w));
}

__global__ __launch_bounds__(NT) void crf_scan_kernel(
    const float* __restrict__ logits,   // (B, 2, T) flat
    const float* __restrict__ trans,    // (2,2)
    float* __restrict__ out,            // out[0]=loss, out[1..]=decoded
    float4* __restrict__ wsM)           // 1024 chunk matrices
{
    __shared__ float4 red[NT / 64];     // one slot per wave

    const int blk = blockIdx.x;         // 0..1023
    const int b   = blk >> 4;           // batch
    const int seg = blk & (NSEG - 1);   // segment within batch
    const int tid = threadIdx.x;
    const float K = 1.4426950408889634f;    // log2(e)

    // Each thread owns 16 consecutive timesteps: 4x float4 per channel, streamed.
    const float4* l0 = (const float4*)(logits + (size_t)b * (2 * T_LEN) + seg * SEG + tid * STEPS);
    const float4* l1 = (const float4*)((const float*)l0 + T_LEN);
    float4* dec = (float4*)(out + 1 + (size_t)b * T_LEN + seg * SEG + tid * STEPS);

    const float t00 = trans[0] * K, t01 = trans[1] * K;
    const float t10 = trans[2] * K, t11 = trans[3] * K;

    float m00, m01, m10, m11;
    auto step = [&](float x0, float x1) {
        const float e0 = x0 * K, e1 = x1 * K;
        const float n00 = e0 + lse2(t00 + m00, t01 + m10);
        const float n01 = e0 + lse2(t00 + m01, t01 + m11);
        const float n10 = e1 + lse2(t10 + m00, t11 + m10);
        const float n11 = e1 + lse2(t10 + m01, t11 + m11);
        m00 = n00; m01 = n01; m10 = n10; m11 = n11;
    };

    {   // chunk 0: init from first element, then 3 steps
        const float4 a = l0[0], c = l1[0];
        dec[0] = make_float4(a.x >= c.x ? 0.0f : 1.0f, a.y >= c.y ? 0.0f : 1.0f,
                             a.z >= c.z ? 0.0f : 1.0f, a.w >= c.w ? 0.0f : 1.0f);
        const float e0 = a.x * K, e1 = c.x * K;
        if (blk == 0 && tid == 0) {     // global t=0: alpha0 = emit_0 as diagonal
            m00 = e0; m11 = e1; m01 = -1e30f; m10 = -1e30f;
        } else {
            m00 = t00 + e0; m01 = t01 + e0;
            m10 = t10 + e1; m11 = t11 + e1;
        }
        step(a.y, c.y); step(a.z, c.z); step(a.w, c.w);
    }
    #pragma unroll 1
    for (int j = 1; j < 4; ++j) {       // small live set: no spill possible
        const float4 a = l0[j], c = l1[j];
        dec[j] = make_float4(a.x >= c.x ? 0.0f : 1.0f, a.y >= c.y ? 0.0f : 1.0f,
                             a.z >= c.z ? 0.0f : 1.0f, a.w >= c.w ? 0.0f : 1.0f);
        step(a.x, c.x); step(a.y, c.y); step(a.z, c.z); step(a.w, c.w);
    }

    // ---- in-wave reduction: 6 shuffle rounds, no barriers ----
    float4 M = make_float4(m00, m01, m10, m11);
    #pragma unroll
    for (int off = 1; off < 64; off <<= 1) {
        float4 Mh;
        Mh.x = __shfl_down(M.x, off);
        Mh.y = __shfl_down(M.y, off);
        Mh.z = __shfl_down(M.z, off);
        Mh.w = __shfl_down(M.w, off);
        const float4 comb = mcomb(Mh, M);   // later (x) earlier
        if ((tid & (2 * off - 1)) == 0) M = comb;
    }
    if ((tid & 63) == 0) red[tid >> 6] = M;
    __syncthreads();

    // ---- combine the 4 wave results ----
    if (tid == 0) {
        float4 Acc = red[0];
        #pragma unroll
        for (int w = 1; w < NT / 64; ++w) Acc = mcomb(red[w], Acc);
        wsM[blk] = Acc;
    }
}

__global__ __launch_bounds__(64) void crf_final_kernel(
    const float4* __restrict__ wsM, float* __restrict__ out)
{
    const int b = threadIdx.x;          // one lane per batch, exactly one wave
    float4 Acc = wsM[b * NSEG];
    #pragma unroll
    for (int s = 1; s < NSEG; ++s) Acc = mcomb(wsM[b * NSEG + s], Acc);
    // alpha_final[i] = LSE_k M[i][k]; LL2_b = LSE_i alpha_final[i]
    float ll2 = lse2(lse2(Acc.x, Acc.y), lse2(Acc.z, Acc.w));
    #pragma unroll
    for (int off = 32; off >= 1; off >>= 1) ll2 += __shfl_xor(ll2, off);
    if (b == 0) out[0] = -(0.6931471805599453f * ll2) * (1.0f / (float)NBATCH);
}

extern "C" void kernel_launch(void* const* d_in, const int* in_sizes, int n_in,
                              void* d_out, int out_size, void* d_ws, size_t ws_size,
                              hipStream_t stream) {
    const float* logits = (const float*)d_in[0];
    // d_in[1] = mask: all-ones and unused by the reference computation
    const float* trans  = (const float*)d_in[2];
    float* out  = (float*)d_out;
    float4* wsM = (float4*)d_ws;    // 1024 * 16 B = 16 KiB

    crf_scan_kernel<<<NBLK, NT, 0, stream>>>(logits, trans, out, wsM);
    crf_final_kernel<<<1, 64, 0, stream>>>(wsM, out);
}

// Round 7
// 97.459 us; speedup vs baseline: 1.3920x; 1.1366x over previous
//
#include <hip/hip_runtime.h>
#include <math.h>

// CRF forward: B=64, C=2, T=65536.
// Log-semiring matrix scan: alpha_t = A_t (x) alpha_{t-1},
//   A_t[i][j] = trans[i][j] + emit_t[i]
// Parallel chunked scan with 2x2 transfer matrices, base-2 logs
// (LSE = 1x v_exp_f32 + 1x v_log_f32, both native HW).
// R7: MLP fix. R5 profile (VALUBusy 7.5%, 590 GB/s, occ 63%) + Little's law
// (2.5 KB in flight/CU x 900cyc = 2.8 B/cyc = measured 600 GB/s) => the
// limiter was outstanding-bytes, not VALU/spills. Now 2048 blocks x 256 thr,
// 8 steps/thread, all 4 dwordx4 loads issued up-front straight-line.

#define T_LEN   65536
#define NT      256       // threads per block (4 waves)
#define STEPS   8         // timesteps per thread
#define SEG     (NT * STEPS)      // 2048 per block
#define NSEG    32        // segments per batch
#define NBATCH  64
#define NBLK    (NBATCH * NSEG)   // 2048 blocks = 8/CU

// __builtin_amdgcn_exp2f = v_exp_f32 (2^x); __builtin_amdgcn_logf = v_log_f32 (log2 x)
__device__ __forceinline__ float lse2(float a, float b) {
    float m = fmaxf(a, b);
    float d = fminf(a, b) - m;          // <= 0; -1e30 inputs give exp2 -> 0, no NaN
    return m + __builtin_amdgcn_logf(1.0f + __builtin_amdgcn_exp2f(d));
}

// C = A (x) B in log-semiring; A = later chunk, B = earlier. (x,y,z,w)=(00,01,10,11)
__device__ __forceinline__ float4 mcomb(float4 A, float4 B) {
    return make_float4(lse2(A.x + B.x, A.y + B.z),
                       lse2(A.x + B.y, A.y + B.w),
                       lse2(A.z + B.x, A.w + B.z),
                       lse2(A.z + B.y, A.w + B.w));
}

__global__ __launch_bounds__(NT) void crf_scan_kernel(
    const float* __restrict__ logits,   // (B, 2, T) flat
    const float* __restrict__ trans,    // (2,2)
    float* __restrict__ out,            // out[0]=loss, out[1..]=decoded
    float4* __restrict__ wsM)           // 2048 chunk matrices
{
    __shared__ float4 red[NT / 64];     // one slot per wave

    const int blk = blockIdx.x;         // 0..2047
    const int b   = blk >> 5;           // batch
    const int seg = blk & (NSEG - 1);   // segment within batch
    const int tid = threadIdx.x;
    const float K = 1.4426950408889634f;    // log2(e)

    // Each thread owns 8 consecutive timesteps: 2x float4 per channel,
    // all four loads independent and issued up-front (max loads in flight).
    const float* l0 = logits + (size_t)b * (2 * T_LEN) + seg * SEG + tid * STEPS;
    const float* l1 = l0 + T_LEN;
    float* dec = out + 1 + (size_t)b * T_LEN + seg * SEG + tid * STEPS;

    const float4 a0 = ((const float4*)l0)[0];
    const float4 a1 = ((const float4*)l0)[1];
    const float4 c0 = ((const float4*)l1)[0];
    const float4 c1 = ((const float4*)l1)[1];

    const float t00 = trans[0] * K, t01 = trans[1] * K;
    const float t10 = trans[2] * K, t11 = trans[3] * K;

    ((float4*)dec)[0] = make_float4(a0.x >= c0.x ? 0.0f : 1.0f,
                                    a0.y >= c0.y ? 0.0f : 1.0f,
                                    a0.z >= c0.z ? 0.0f : 1.0f,
                                    a0.w >= c0.w ? 0.0f : 1.0f);
    ((float4*)dec)[1] = make_float4(a1.x >= c1.x ? 0.0f : 1.0f,
                                    a1.y >= c1.y ? 0.0f : 1.0f,
                                    a1.z >= c1.z ? 0.0f : 1.0f,
                                    a1.w >= c1.w ? 0.0f : 1.0f);

    // ---- per-thread sequential scan over 8 steps (2x2 transfer matrix) ----
    float m00, m01, m10, m11;
    {
        const float e0 = a0.x * K, e1 = c0.x * K;
        if (blk == 0 && tid == 0) {     // global t=0: alpha0 = emit_0 as diagonal
            m00 = e0; m11 = e1; m01 = -1e30f; m10 = -1e30f;
        } else {
            m00 = t00 + e0; m01 = t01 + e0;
            m10 = t10 + e1; m11 = t11 + e1;
        }
    }
    auto step = [&](float x0, float x1) {
        const float e0 = x0 * K, e1 = x1 * K;
        const float n00 = e0 + lse2(t00 + m00, t01 + m10);
        const float n01 = e0 + lse2(t00 + m01, t01 + m11);
        const float n10 = e1 + lse2(t10 + m00, t11 + m10);
        const float n11 = e1 + lse2(t10 + m01, t11 + m11);
        m00 = n00; m01 = n01; m10 = n10; m11 = n11;
    };
    step(a0.y, c0.y); step(a0.z, c0.z); step(a0.w, c0.w);
    step(a1.x, c1.x); step(a1.y, c1.y); step(a1.z, c1.z); step(a1.w, c1.w);

    // ---- in-wave reduction: 6 shuffle rounds, no barriers ----
    float4 M = make_float4(m00, m01, m10, m11);
    #pragma unroll
    for (int off = 1; off < 64; off <<= 1) {
        float4 Mh;
        Mh.x = __shfl_down(M.x, off);
        Mh.y = __shfl_down(M.y, off);
        Mh.z = __shfl_down(M.z, off);
        Mh.w = __shfl_down(M.w, off);
        const float4 comb = mcomb(Mh, M);   // later (x) earlier
        if ((tid & (2 * off - 1)) == 0) M = comb;
    }
    if ((tid & 63) == 0) red[tid >> 6] = M;
    __syncthreads();

    // ---- combine the 4 wave results ----
    if (tid == 0) {
        float4 Acc = red[0];
        #pragma unroll
        for (int w = 1; w < NT / 64; ++w) Acc = mcomb(red[w], Acc);
        wsM[blk] = Acc;
    }
}

__global__ __launch_bounds__(64) void crf_final_kernel(
    const float4* __restrict__ wsM, float* __restrict__ out)
{
    const int b = threadIdx.x;          // one lane per batch, exactly one wave
    float4 Acc = wsM[b * NSEG];
    #pragma unroll
    for (int s = 1; s < NSEG; ++s) Acc = mcomb(wsM[b * NSEG + s], Acc);
    // alpha_final[i] = LSE_k M[i][k]; LL2_b = LSE_i alpha_final[i]
    float ll2 = lse2(lse2(Acc.x, Acc.y), lse2(Acc.z, Acc.w));
    #pragma unroll
    for (int off = 32; off >= 1; off >>= 1) ll2 += __shfl_xor(ll2, off);
    if (b == 0) out[0] = -(0.6931471805599453f * ll2) * (1.0f / (float)NBATCH);
}

extern "C" void kernel_launch(void* const* d_in, const int* in_sizes, int n_in,
                              void* d_out, int out_size, void* d_ws, size_t ws_size,
                              hipStream_t stream) {
    const float* logits = (const float*)d_in[0];
    // d_in[1] = mask: all-ones and unused by the reference computation
    const float* trans  = (const float*)d_in[2];
    float* out  = (float*)d_out;
    float4* wsM = (float4*)d_ws;    // 2048 * 16 B = 32 KiB

    crf_scan_kernel<<<NBLK, NT, 0, stream>>>(logits, trans, out, wsM);
    crf_final_kernel<<<1, 64, 0, stream>>>(wsM, out);
}